// Round 1
// baseline (3213.529 us; speedup 1.0000x reference)
//
#include <hip/hip_runtime.h>
#include <hip/hip_bf16.h>

#define BB 256
#define TT 512
#define DD 256
#define HH 512
#define G4H 2048
#define KTOT 768
#define APITCH 1552   // 768*2 + 16B pad: row stride ≡ 4 banks (mod 32) -> conflict-free b128
#define WPITCH 1552

typedef unsigned short u16;
typedef __attribute__((ext_vector_type(8))) short bf16x8;   // 8 bf16 (4 VGPRs)
typedef __attribute__((ext_vector_type(4))) float f32x4;

__device__ __forceinline__ u16 f2bf(float f) {
  union { float f; unsigned u; } v; v.f = f;
  unsigned r = v.u + 0x7FFFu + ((v.u >> 16) & 1u);   // round-to-nearest-even
  return (u16)(r >> 16);
}
__device__ __forceinline__ float bf2f(u16 b) {
  union { unsigned u; float f; } v; v.u = ((unsigned)b) << 16;
  return v.f;
}
__device__ __forceinline__ float fsigmoid(float x) { return 1.f / (1.f + __expf(-x)); }
__device__ __forceinline__ float ftanh(float x) { return 1.f - 2.f / (__expf(2.f * x) + 1.f); }

// Build Wc = [W_hh | W_ih] in bf16 [2048][768]; bsum = b_ih + b_hh; zero h0, c.
__global__ __launch_bounds__(256) void lstm_init(
    const float* __restrict__ W_ih, const float* __restrict__ W_hh,
    const float* __restrict__ b_ih, const float* __restrict__ b_hh,
    u16* __restrict__ Wc, float* __restrict__ bsum,
    u16* __restrict__ h0, float* __restrict__ c_ws)
{
  int idx = blockIdx.x * 256 + threadIdx.x;
  if (idx < G4H * KTOT) {
    int r = idx / KTOT, k = idx - r * KTOT;
    float v = (k < HH) ? W_hh[r * HH + k] : W_ih[r * DD + (k - HH)];
    Wc[idx] = f2bf(v);
  }
  if (idx < G4H) bsum[idx] = b_ih[idx] + b_hh[idx];
  if (idx < BB * HH) { h0[idx] = (u16)0; c_ws[idx] = 0.f; }
}

// One timestep. Grid: 256 WGs x 256 threads. WG = (batch group bg of 32) x (hidden slice sl of 16).
// gates[b, n] over K=768 = [h | x_t] . Wc^T, then fused i/f/g/o pointwise update.
__global__ __launch_bounds__(256) void lstm_step(
    const float* __restrict__ x, const u16* __restrict__ Wc,
    const float* __restrict__ bsum, u16* __restrict__ h_buf,
    float* __restrict__ c_ws, int t)
{
  __shared__ __align__(16) unsigned char Alds[32 * APITCH];   // 49,664 B: [h|x] tile, 32 x 768 bf16
  __shared__ __align__(16) unsigned char Wlds[64 * WPITCH];   // 99,328 B: 64 gate rows x 768 bf16
  __shared__ float g4[4][32][16];                             //  8,192 B: gate quarters

  const int tid = threadIdx.x;
  const int bg = blockIdx.x >> 5;   // 0..7  : batches [32*bg, 32*bg+32)
  const int sl = blockIdx.x & 31;   // 0..31 : hidden units [16*sl, 16*sl+16)
  const int cur = t & 1;
  const u16* __restrict__ h_in = h_buf + cur * (BB * HH);
  u16* __restrict__ h_out = h_buf + (cur ^ 1) * (BB * HH);

  // ---- stage A, h part (k 0..511): 32 rows x 1KB, 2048 x 16B chunks
  {
    const u16* hb = h_in + (size_t)bg * 32 * HH;
    #pragma unroll
    for (int j = 0; j < 8; ++j) {
      int c = tid + j * 256;
      int row = c >> 6, col = c & 63;
      bf16x8 v = *(const bf16x8*)(hb + row * HH + col * 8);
      *(bf16x8*)(Alds + row * APITCH + col * 16) = v;
    }
  }
  // ---- stage A, x part (k 512..767): 32 rows x 256 f32 -> bf16
  {
    const float* xb = x + ((size_t)bg * 32 * TT + t) * DD;
    #pragma unroll
    for (int j = 0; j < 8; ++j) {
      int c = tid + j * 256;
      int row = c >> 6, col = c & 63;
      float4 v = *(const float4*)(xb + (size_t)row * TT * DD + col * 4);
      unsigned lo = (unsigned)f2bf(v.x) | ((unsigned)f2bf(v.y) << 16);
      unsigned hi = (unsigned)f2bf(v.z) | ((unsigned)f2bf(v.w) << 16);
      *(uint2*)(Alds + row * APITCH + 1024 + col * 8) = make_uint2(lo, hi);
    }
  }
  // ---- stage W slice: rows r=q*16+u <-> Wc row q*512 + sl*16 + u; 6144 x 16B chunks
  {
    #pragma unroll
    for (int j = 0; j < 24; ++j) {
      int c = tid + j * 256;
      int r = c / 96;
      int col = c - r * 96;
      int q = r >> 4, u = r & 15;
      const u16* src = Wc + (size_t)(q * HH + sl * 16 + u) * KTOT + col * 8;
      bf16x8 v = *(const bf16x8*)src;
      *(bf16x8*)(Wlds + r * WPITCH + col * 16) = v;
    }
  }
  __syncthreads();

  // ---- MFMA: wave wv computes gate quarter wv: D[32 b x 16 n], K=768 in 24 chunks
  const int lane = tid & 63;
  const int wv = tid >> 6;
  const int lrow = lane & 15;   // A row m / B col n
  const int lkb = lane >> 4;    // k-block: k = lkb*8 + j
  f32x4 acc0 = {0.f, 0.f, 0.f, 0.f};
  f32x4 acc1 = {0.f, 0.f, 0.f, 0.f};
  const unsigned ao0 = (unsigned)(lrow * APITCH + lkb * 16);
  const unsigned ao1 = ao0 + 16u * APITCH;
  const unsigned wo  = (unsigned)((wv * 16 + lrow) * WPITCH + lkb * 16);
  #pragma unroll
  for (int kc = 0; kc < 24; ++kc) {
    bf16x8 bf = *(const bf16x8*)(Wlds + wo  + kc * 64);
    bf16x8 a0 = *(const bf16x8*)(Alds + ao0 + kc * 64);
    bf16x8 a1 = *(const bf16x8*)(Alds + ao1 + kc * 64);
    acc0 = __builtin_amdgcn_mfma_f32_16x16x32_bf16(a0, bf, acc0, 0, 0, 0);
    acc1 = __builtin_amdgcn_mfma_f32_16x16x32_bf16(a1, bf, acc1, 0, 0, 0);
  }
  // C/D layout (m89-verified): col = lane&15, row = (lane>>4)*4 + reg
  #pragma unroll
  for (int r = 0; r < 4; ++r) {
    g4[wv][lkb * 4 + r][lrow]      = acc0[r];
    g4[wv][16 + lkb * 4 + r][lrow] = acc1[r];
  }
  __syncthreads();

  // ---- pointwise LSTM cell update: 512 (b,u) elements, 2 per thread
  #pragma unroll
  for (int e = tid; e < 512; e += 256) {
    int b = e >> 4, u = e & 15;
    int hu = sl * 16 + u;
    float gi = g4[0][b][u] + bsum[hu];
    float gf = g4[1][b][u] + bsum[HH + hu];
    float gg = g4[2][b][u] + bsum[2 * HH + hu];
    float go = g4[3][b][u] + bsum[3 * HH + hu];
    int gb = bg * 32 + b;
    float c_old = c_ws[gb * HH + hu];
    float cn = fsigmoid(gf) * c_old + fsigmoid(gi) * ftanh(gg);
    float hn = fsigmoid(go) * ftanh(cn);
    c_ws[gb * HH + hu] = cn;
    h_out[gb * HH + hu] = f2bf(hn);
  }
}

// out[b] = sigmoid(h_T[b,:] . fc_w + fc_b)
__global__ __launch_bounds__(256) void lstm_final(
    const u16* __restrict__ h, const float* __restrict__ fc_w,
    const float* __restrict__ fc_b, float* __restrict__ out)
{
  int b = threadIdx.x;
  float s = 0.f;
  const u16* hp = h + (size_t)b * HH;
  #pragma unroll 8
  for (int k = 0; k < HH; k += 8) {
    bf16x8 v = *(const bf16x8*)(hp + k);
    #pragma unroll
    for (int j = 0; j < 8; ++j) s += bf2f((u16)v[j]) * fc_w[k + j];
  }
  s += fc_b[0];
  out[b] = fsigmoid(s);
}

extern "C" void kernel_launch(void* const* d_in, const int* in_sizes, int n_in,
                              void* d_out, int out_size, void* d_ws, size_t ws_size,
                              hipStream_t stream) {
  (void)in_sizes; (void)n_in; (void)out_size; (void)ws_size;
  const float* x    = (const float*)d_in[0];
  const float* W_ih = (const float*)d_in[1];
  const float* W_hh = (const float*)d_in[2];
  const float* b_ih = (const float*)d_in[3];
  const float* b_hh = (const float*)d_in[4];
  const float* fc_w = (const float*)d_in[5];
  const float* fc_b = (const float*)d_in[6];
  float* out = (float*)d_out;

  char* ws = (char*)d_ws;
  u16*   Wc    = (u16*)(ws);                 // 2048*768*2  = 3,145,728 B
  float* bsum  = (float*)(ws + 3145728);     // 2048*4      =     8,192 B
  u16*   h_buf = (u16*)(ws + 3153920);       // 2*256*512*2 =   524,288 B
  float* c_ws  = (float*)(ws + 3678208);     // 256*512*4   =   524,288 B
                                             // total ~4.2 MB

  lstm_init<<<6144, 256, 0, stream>>>(W_ih, W_hh, b_ih, b_hh, Wc, bsum, h_buf, c_ws);
  for (int t = 0; t < TT; ++t)
    lstm_step<<<256, 256, 0, stream>>>(x, Wc, bsum, h_buf, c_ws, t);
  lstm_final<<<1, 256, 0, stream>>>(h_buf, fc_w, fc_b, out);
}